// Round 1
// baseline (954.340 us; speedup 1.0000x reference)
//
#include <hip/hip_runtime.h>
#include <hip/hip_bf16.h>

// GNN multi-edgeset: atom-enc -> 2x GINE(gather+agg, MLP) -> head -> masked mean pool
// All fp32. Constants hardcoded to the problem: H=128, Fe=16, Fin=64, L=2, O=32, RC=8.

#define H 128
#define FIN 64
#define FE 16
#define OO 32
#define RCN 8

__device__ __forceinline__ float gelu_exact(float v) {
    return 0.5f * v * (1.0f + erff(v * 0.70710678118654752440f));
}

// ---------------- CSR build ----------------
__global__ void k_zero_i32(int* p, int n) {
    int i = blockIdx.x * blockDim.x + threadIdx.x;
    if (i < n) p[i] = 0;
}

__global__ void k_hist(const int* __restrict__ ei, int* __restrict__ deg, int E) {
    int e = blockIdx.x * blockDim.x + threadIdx.x;
    if (e < E) atomicAdd(&deg[ei[E + e]], 1);   // dst
}

__global__ void k_scan(const int* __restrict__ deg, int* __restrict__ off,
                       int* __restrict__ cursor, int N) {
    __shared__ int s[1024];
    __shared__ int carry_s;
    int t = threadIdx.x;
    if (t == 0) { carry_s = 0; off[0] = 0; }
    __syncthreads();
    for (int base = 0; base < N; base += 1024) {
        int v = (base + t < N) ? deg[base + t] : 0;
        for (int d = 1; d < 1024; d <<= 1) {
            s[t] = v; __syncthreads();
            if (t >= d) v += s[t - d];
            __syncthreads();
        }
        int carry = carry_s;
        if (base + t < N) off[base + t + 1] = carry + v;
        __syncthreads();
        if (t == 1023) carry_s = carry + v;
        __syncthreads();
    }
    for (int i = t; i < N; i += 1024) cursor[i] = off[i];
}

__global__ void k_scatter(const int* __restrict__ ei, int* __restrict__ cursor,
                          int* __restrict__ elist, int E) {
    int e = blockIdx.x * blockDim.x + threadIdx.x;
    if (e < E) {
        int d = ei[E + e];
        int pos = atomicAdd(&cursor[d], 1);
        elist[pos] = e;
    }
}

__global__ void k_gstart(const int* __restrict__ batch, int* __restrict__ gstart,
                         int N, int G) {
    int g = blockIdx.x * blockDim.x + threadIdx.x;
    if (g > G) return;
    int lo = 0, hi = N;
    while (lo < hi) { int mid = (lo + hi) >> 1; if (batch[mid] < g) lo = mid + 1; else hi = mid; }
    gstart[g] = lo;
}

// node_mask [RC][N] -> nmT [N][RC]
__global__ void k_nmt(const float* __restrict__ nm, float* __restrict__ nmT, int N) {
    int idx = blockIdx.x * blockDim.x + threadIdx.x;
    if (idx < N * RCN) {
        int n = idx >> 3, rc = idx & 7;
        nmT[idx] = nm[rc * N + n];
    }
}

// ---------------- encoders ----------------
__global__ __launch_bounds__(H) void k_atom(const float* __restrict__ xf,
                                            const float* __restrict__ W,
                                            const float* __restrict__ b,
                                            float* __restrict__ x, int N) {
    int n = blockIdx.x, j = threadIdx.x;
    __shared__ float s[FIN];
    if (j < FIN) s[j] = xf[n * FIN + j];
    __syncthreads();
    float acc = b[j];
#pragma unroll
    for (int k = 0; k < FIN; k++) acc += s[k] * W[k * H + j];
    x[(size_t)n * H + j] = acc;
}

__global__ __launch_bounds__(H) void k_emb(const float* __restrict__ ea,
                                           const float* __restrict__ W,
                                           const float* __restrict__ b,
                                           float* __restrict__ emb, int E) {
    int e = blockIdx.x, l = blockIdx.y, j = threadIdx.x;
    __shared__ float s[FE];
    if (j < FE) s[j] = ea[e * FE + j];
    __syncthreads();
    float acc = b[l * H + j];
#pragma unroll
    for (int k = 0; k < FE; k++) acc += s[k] * W[(l * FE + k) * H + j];
    emb[((size_t)l * E + e) * H + j] = acc;
}

// ---------------- gather + aggregate ----------------
// layer 0: ux identical across rc -> compute gelu once per edge
__global__ __launch_bounds__(H) void k_gather0(
    const float* __restrict__ x, const float* __restrict__ emb0,
    const float* __restrict__ nmT, const int* __restrict__ ei,
    const int* __restrict__ off, const int* __restrict__ elist,
    const float* __restrict__ epsp, float* __restrict__ outB, int N) {
    int n = blockIdx.x, j = threadIdx.x;
    float xj = x[(size_t)n * H + j];
    float acc[8] = {0, 0, 0, 0, 0, 0, 0, 0};
    int e0 = off[n], e1 = off[n + 1];
    for (int idx = e0; idx < e1; ++idx) {
        int e = elist[idx];
        int s = ei[e];   // src
        float g = gelu_exact(x[(size_t)s * H + j] + emb0[(size_t)e * H + j]);
        float4 m0 = *(const float4*)(nmT + s * 8);
        float4 m1 = *(const float4*)(nmT + s * 8 + 4);
        acc[0] += g * m0.x; acc[1] += g * m0.y; acc[2] += g * m0.z; acc[3] += g * m0.w;
        acc[4] += g * m1.x; acc[5] += g * m1.y; acc[6] += g * m1.z; acc[7] += g * m1.w;
    }
    float ev = 1.0f + epsp[0];
    float4 mn0 = *(const float4*)(nmT + n * 8);
    float4 mn1 = *(const float4*)(nmT + n * 8 + 4);
    float mn[8] = {mn0.x, mn0.y, mn0.z, mn0.w, mn1.x, mn1.y, mn1.z, mn1.w};
#pragma unroll
    for (int rc = 0; rc < 8; ++rc)
        outB[((size_t)rc * N + n) * H + j] = ev * xj + mn[rc] * acc[rc];
}

// layer 1: ux differs per rc
__global__ __launch_bounds__(H) void k_gather1(
    const float* __restrict__ ux, const float* __restrict__ emb1,
    const float* __restrict__ nmT, const int* __restrict__ ei,
    const int* __restrict__ off, const int* __restrict__ elist,
    const float* __restrict__ epsp, float* __restrict__ outB, int N) {
    int n = blockIdx.x, r = blockIdx.y, j = threadIdx.x;
    const float* uxr = ux + (size_t)r * N * H;
    float acc = 0.f;
    int e0 = off[n], e1 = off[n + 1];
    for (int idx = e0; idx < e1; ++idx) {
        int e = elist[idx];
        int s = ei[e];
        float g = gelu_exact(uxr[(size_t)s * H + j] + emb1[(size_t)e * H + j]);
        acc += g * nmT[s * 8 + r];
    }
    float ev = 1.0f + epsp[1];
    float h = ev * uxr[(size_t)n * H + j] + nmT[n * 8 + r] * acc;
    outB[((size_t)r * N + n) * H + j] = h;
}

// ---------------- GEMM: C[M x 128] = act(A[M x 128] @ W[128 x 128] + b) ----------------
// 64-row tile per 128-thread block; 8x8 register accumulators; no LDS (L1/L2 serve
// broadcast A-fragments and streamed W). ACT=1 -> exact-erf GELU epilogue.
template <int ACT>
__global__ __launch_bounds__(128) void k_gemm128(
    const float* __restrict__ A, const float* __restrict__ W,
    const float* __restrict__ bias, float* __restrict__ C, int M) {
    const int ty = threadIdx.x >> 4;        // 0..7  -> 8-row group
    const int tx = threadIdx.x & 15;        // 0..15 -> 8-col group
    const int r0 = blockIdx.x * 64 + ty * 8;
    const int c0 = tx * 8;

    float acc[8][8];
#pragma unroll
    for (int i = 0; i < 8; i++)
#pragma unroll
        for (int j = 0; j < 8; j++) acc[i][j] = 0.f;

    const float* Arow[8];
#pragma unroll
    for (int i = 0; i < 8; i++) {
        int r = r0 + i; if (r > M - 1) r = M - 1;
        Arow[i] = A + (size_t)r * H;
    }

    for (int k = 0; k < H; k += 4) {
        float4 a4[8];
#pragma unroll
        for (int i = 0; i < 8; i++) a4[i] = *(const float4*)(Arow[i] + k);
        float4 w0[4], w1[4];
#pragma unroll
        for (int kk = 0; kk < 4; kk++) {
            w0[kk] = *(const float4*)(W + (size_t)(k + kk) * H + c0);
            w1[kk] = *(const float4*)(W + (size_t)(k + kk) * H + c0 + 4);
        }
#pragma unroll
        for (int kk = 0; kk < 4; kk++) {
#pragma unroll
            for (int i = 0; i < 8; i++) {
                float av = (kk == 0) ? a4[i].x : (kk == 1) ? a4[i].y : (kk == 2) ? a4[i].z : a4[i].w;
                acc[i][0] += av * w0[kk].x; acc[i][1] += av * w0[kk].y;
                acc[i][2] += av * w0[kk].z; acc[i][3] += av * w0[kk].w;
                acc[i][4] += av * w1[kk].x; acc[i][5] += av * w1[kk].y;
                acc[i][6] += av * w1[kk].z; acc[i][7] += av * w1[kk].w;
            }
        }
    }

    float4 b0 = *(const float4*)(bias + c0);
    float4 b1 = *(const float4*)(bias + c0 + 4);
    float bb[8] = {b0.x, b0.y, b0.z, b0.w, b1.x, b1.y, b1.z, b1.w};
#pragma unroll
    for (int i = 0; i < 8; i++) {
        if (r0 + i >= M) break;
        float out[8];
#pragma unroll
        for (int j = 0; j < 8; j++) {
            float v = acc[i][j] + bb[j];
            out[j] = ACT ? gelu_exact(v) : v;
        }
        float* Cp = C + (size_t)(r0 + i) * H + c0;
        *(float4*)Cp = make_float4(out[0], out[1], out[2], out[3]);
        *(float4*)(Cp + 4) = make_float4(out[4], out[5], out[6], out[7]);
    }
}

// ---------------- pooling (in H-space; head2 is linear so it commutes) ----------------
__global__ __launch_bounds__(512) void k_pool_h(
    const float* __restrict__ hin, const float* __restrict__ nmT,
    const int* __restrict__ gstart, float* __restrict__ pooled,
    float* __restrict__ denb, int N, int G) {
    int g = blockIdx.x, r = blockIdx.y;
    int j = threadIdx.x & 127, q = threadIdx.x >> 7;   // 4 node stripes
    int n0 = gstart[g], n1 = gstart[g + 1];
    const float* hr = hin + (size_t)r * N * H;
    float num = 0.f, den = 0.f;
    for (int n = n0 + q; n < n1; n += 4) {
        float m = nmT[n * 8 + r];
        num += hr[(size_t)n * H + j] * m;
        den += m;
    }
    __shared__ float sn[512];
    __shared__ float sd[4];
    sn[threadIdx.x] = num;
    if (j == 0) sd[q] = den;
    __syncthreads();
    if (q == 0) {
        float numt = sn[j] + sn[128 + j] + sn[256 + j] + sn[384 + j];
        float dent = sd[0] + sd[1] + sd[2] + sd[3];
        pooled[((size_t)r * G + g) * H + j] = numt;
        if (j == 0) denb[r * G + g] = dent;
    }
}

// out[row][o] = (pooled[row] @ W2 + den*b2) / (den + 1e-7), row = rc*G+g
__global__ __launch_bounds__(128) void k_head2s(
    const float* __restrict__ pooled, const float* __restrict__ denb,
    const float* __restrict__ W, const float* __restrict__ bias,
    float* __restrict__ outp) {
    int row = blockIdx.x;
    int o = threadIdx.x & 31, kq = threadIdx.x >> 5;
    const float* p = pooled + (size_t)row * H;
    float acc = 0.f;
#pragma unroll
    for (int kk = 0; kk < 32; ++kk) {
        int k = kq * 32 + kk;
        acc += p[k] * W[k * OO + o];
    }
    __shared__ float s[128];
    s[threadIdx.x] = acc; __syncthreads();
    if (kq == 0) {
        float den = denb[row];
        float num = s[o] + s[32 + o] + s[64 + o] + s[96 + o] + den * bias[o];
        outp[row * OO + o] = num / (den + 1e-7f);
    }
}

extern "C" void kernel_launch(void* const* d_in, const int* in_sizes, int n_in,
                              void* d_out, int out_size, void* d_ws, size_t ws_size,
                              hipStream_t stream) {
    const float* x_feat = (const float*)d_in[0];
    const int*   ei     = (const int*)d_in[1];
    const float* eattr  = (const float*)d_in[2];
    const int*   batch  = (const int*)d_in[3];
    const float* nm     = (const float*)d_in[4];
    const float* atomW  = (const float*)d_in[5];
    const float* atomb  = (const float*)d_in[6];
    const float* epsp   = (const float*)d_in[7];
    const float* bondW  = (const float*)d_in[8];
    const float* bondb  = (const float*)d_in[9];
    const float* mlp1W  = (const float*)d_in[10];
    const float* mlp1b  = (const float*)d_in[11];
    const float* mlp2W  = (const float*)d_in[12];
    const float* mlp2b  = (const float*)d_in[13];
    const float* h1W    = (const float*)d_in[14];
    const float* h1b    = (const float*)d_in[15];
    const float* h2W    = (const float*)d_in[16];
    const float* h2b    = (const float*)d_in[17];

    const int N  = in_sizes[3];
    const int E  = in_sizes[1] / 2;
    const int G  = out_size / (RCN * OO);
    const int M  = RCN * N;

    float* x      = (float*)d_ws;
    float* emb    = x + (size_t)N * H;
    float* bufA   = emb + (size_t)2 * E * H;
    float* bufB   = bufA + (size_t)RCN * N * H;
    float* nmT    = bufB + (size_t)RCN * N * H;
    float* pooled = nmT + (size_t)N * RCN;
    float* denb   = pooled + (size_t)RCN * G * H;
    int*   deg    = (int*)(denb + RCN * G);
    int*   off    = deg + N;
    int*   cursor = off + N + 1;
    int*   elist  = cursor + N;
    int*   gstart = elist + E;

    // CSR by dst + graph ranges + transposed node mask
    k_zero_i32<<<(N + 255) / 256, 256, 0, stream>>>(deg, N);
    k_hist<<<(E + 255) / 256, 256, 0, stream>>>(ei, deg, E);
    k_scan<<<1, 1024, 0, stream>>>(deg, off, cursor, N);
    k_scatter<<<(E + 255) / 256, 256, 0, stream>>>(ei, cursor, elist, E);
    k_gstart<<<1, 128, 0, stream>>>(batch, gstart, N, G);
    k_nmt<<<(N * RCN + 255) / 256, 256, 0, stream>>>(nm, nmT, N);

    // encoders
    k_atom<<<N, H, 0, stream>>>(x_feat, atomW, atomb, x, N);
    k_emb<<<dim3(E, 2), H, 0, stream>>>(eattr, bondW, bondb, emb, E);

    // layer 0
    k_gather0<<<N, H, 0, stream>>>(x, emb, nmT, ei, off, elist, epsp, bufB, N);
    k_gemm128<1><<<(M + 63) / 64, 128, 0, stream>>>(bufB, mlp1W, mlp1b, bufA, M);
    k_gemm128<1><<<(M + 63) / 64, 128, 0, stream>>>(bufA, mlp2W, mlp2b, bufB, M);  // ux1 -> bufB

    // layer 1
    k_gather1<<<dim3(N, RCN), H, 0, stream>>>(bufB, emb + (size_t)E * H, nmT, ei, off, elist,
                                              epsp, bufA, N);
    k_gemm128<1><<<(M + 63) / 64, 128, 0, stream>>>(bufA, mlp1W + H * H, mlp1b + H, bufB, M);
    k_gemm128<1><<<(M + 63) / 64, 128, 0, stream>>>(bufB, mlp2W + H * H, mlp2b + H, bufA, M);  // ux2 -> bufA

    // head1 + pool (head2 commuted past pooling)
    k_gemm128<1><<<(M + 63) / 64, 128, 0, stream>>>(bufA, h1W, h1b, bufB, M);
    k_pool_h<<<dim3(G, RCN), 512, 0, stream>>>(bufB, nmT, gstart, pooled, denb, N, G);
    k_head2s<<<RCN * G, 128, 0, stream>>>(pooled, denb, h2W, h2b, (float*)d_out);
}

// Round 2
// 592.989 us; speedup vs baseline: 1.6094x; 1.6094x over previous
//
#include <hip/hip_runtime.h>
#include <hip/hip_bf16.h>

// GNN multi-edgeset: atom-enc -> 2x GINE(gather+agg, fused MLP) -> head -> masked mean pool
// fp32 I/O; GEMMs via bf16x3-split MFMA (16x16x32). H=128, Fe=16, Fin=64, L=2, O=32, RC=8.

#define H 128
#define FIN 64
#define FE 16
#define OO 32
#define RCN 8

typedef __attribute__((ext_vector_type(8))) short short8v;
typedef __attribute__((ext_vector_type(4))) float f32x4;

__device__ __forceinline__ float gelu_exact(float v) {
    return 0.5f * v * (1.0f + erff(v * 0.70710678118654752440f));
}
__device__ __forceinline__ unsigned short f2bf(float f) {
    unsigned u = __float_as_uint(f);
    unsigned r = u + 0x7FFFu + ((u >> 16) & 1u);
    return (unsigned short)(r >> 16);
}
__device__ __forceinline__ float bf2f(unsigned short b) {
    return __uint_as_float(((unsigned)b) << 16);
}
__device__ __forceinline__ f32x4 mfma16(short8v a, short8v b, f32x4 c) {
    return __builtin_amdgcn_mfma_f32_16x16x32_bf16(a, b, c, 0, 0, 0);
}

// ---------------- CSR build ----------------
__global__ void k_zero_i32(int* p, int n) {
    int i = blockIdx.x * blockDim.x + threadIdx.x;
    if (i < n) p[i] = 0;
}

__global__ void k_hist(const int* __restrict__ ei, int* __restrict__ deg, int E) {
    int e = blockIdx.x * blockDim.x + threadIdx.x;
    if (e < E) atomicAdd(&deg[ei[E + e]], 1);   // dst
}

__global__ void k_scan(const int* __restrict__ deg, int* __restrict__ off,
                       int* __restrict__ cursor, int N) {
    __shared__ int s[1024];
    __shared__ int carry_s;
    int t = threadIdx.x;
    if (t == 0) { carry_s = 0; off[0] = 0; }
    __syncthreads();
    for (int base = 0; base < N; base += 1024) {
        int v = (base + t < N) ? deg[base + t] : 0;
        for (int d = 1; d < 1024; d <<= 1) {
            s[t] = v; __syncthreads();
            if (t >= d) v += s[t - d];
            __syncthreads();
        }
        int carry = carry_s;
        if (base + t < N) off[base + t + 1] = carry + v;
        __syncthreads();
        if (t == 1023) carry_s = carry + v;
        __syncthreads();
    }
    for (int i = t; i < N; i += 1024) cursor[i] = off[i];
}

__global__ void k_scatter(const int* __restrict__ ei, int* __restrict__ cursor,
                          int* __restrict__ elist, int E) {
    int e = blockIdx.x * blockDim.x + threadIdx.x;
    if (e < E) {
        int d = ei[E + e];
        int pos = atomicAdd(&cursor[d], 1);
        elist[pos] = e;
    }
}

__global__ void k_gstart(const int* __restrict__ batch, int* __restrict__ gstart,
                         int N, int G) {
    int g = blockIdx.x * blockDim.x + threadIdx.x;
    if (g > G) return;
    int lo = 0, hi = N;
    while (lo < hi) { int mid = (lo + hi) >> 1; if (batch[mid] < g) lo = mid + 1; else hi = mid; }
    gstart[g] = lo;
}

// node_mask [RC][N] -> nmT [N][RC]
__global__ void k_nmt(const float* __restrict__ nm, float* __restrict__ nmT, int N) {
    int idx = blockIdx.x * blockDim.x + threadIdx.x;
    if (idx < N * RCN) {
        int n = idx >> 3, rc = idx & 7;
        nmT[idx] = nm[rc * N + n];
    }
}

// ---------------- weight split: W[k][n] fp32 -> WhT/WlT [n][k] bf16 ----------------
__global__ __launch_bounds__(H) void k_splitW(const float* __restrict__ W,
                                              unsigned short* __restrict__ WhT,
                                              unsigned short* __restrict__ WlT) {
    int k = blockIdx.x, n = threadIdx.x;
    float v = W[k * H + n];
    unsigned short h = f2bf(v);
    WhT[n * H + k] = h;
    WlT[n * H + k] = f2bf(v - bf2f(h));
}

// ---------------- encoders ----------------
__global__ __launch_bounds__(H) void k_atom(const float* __restrict__ xf,
                                            const float* __restrict__ W,
                                            const float* __restrict__ b,
                                            float* __restrict__ x, int N) {
    int n = blockIdx.x, j = threadIdx.x;
    __shared__ float s[FIN];
    if (j < FIN) s[j] = xf[n * FIN + j];
    __syncthreads();
    float acc = b[j];
#pragma unroll
    for (int k = 0; k < FIN; k++) acc += s[k] * W[k * H + j];
    x[(size_t)n * H + j] = acc;
}

__global__ __launch_bounds__(H) void k_emb(const float* __restrict__ ea,
                                           const float* __restrict__ W,
                                           const float* __restrict__ b,
                                           float* __restrict__ emb, int E) {
    int e = blockIdx.x, l = blockIdx.y, j = threadIdx.x;
    __shared__ float s[FE];
    if (j < FE) s[j] = ea[e * FE + j];
    __syncthreads();
    float acc = b[l * H + j];
#pragma unroll
    for (int k = 0; k < FE; k++) acc += s[k] * W[(l * FE + k) * H + j];
    emb[((size_t)l * E + e) * H + j] = acc;
}

// ---------------- gather + aggregate ----------------
// layer 0: ux identical across rc -> compute gelu once per edge
__global__ __launch_bounds__(H) void k_gather0(
    const float* __restrict__ x, const float* __restrict__ emb0,
    const float* __restrict__ nmT, const int* __restrict__ ei,
    const int* __restrict__ off, const int* __restrict__ elist,
    const float* __restrict__ epsp, float* __restrict__ outB, int N) {
    int n = blockIdx.x, j = threadIdx.x;
    float xj = x[(size_t)n * H + j];
    float acc[8] = {0, 0, 0, 0, 0, 0, 0, 0};
    int e0 = off[n], e1 = off[n + 1];
    for (int idx = e0; idx < e1; ++idx) {
        int e = elist[idx];
        int s = ei[e];   // src
        float g = gelu_exact(x[(size_t)s * H + j] + emb0[(size_t)e * H + j]);
        float4 m0 = *(const float4*)(nmT + s * 8);
        float4 m1 = *(const float4*)(nmT + s * 8 + 4);
        acc[0] += g * m0.x; acc[1] += g * m0.y; acc[2] += g * m0.z; acc[3] += g * m0.w;
        acc[4] += g * m1.x; acc[5] += g * m1.y; acc[6] += g * m1.z; acc[7] += g * m1.w;
    }
    float ev = 1.0f + epsp[0];
    float4 mn0 = *(const float4*)(nmT + n * 8);
    float4 mn1 = *(const float4*)(nmT + n * 8 + 4);
    float mn[8] = {mn0.x, mn0.y, mn0.z, mn0.w, mn1.x, mn1.y, mn1.z, mn1.w};
#pragma unroll
    for (int rc = 0; rc < 8; ++rc)
        outB[((size_t)rc * N + n) * H + j] = ev * xj + mn[rc] * acc[rc];
}

// layer 1: all 8 rc in one block -> emb read ONCE per edge (was 8x -> 315MB HBM fetch)
__global__ __launch_bounds__(H) void k_gather1(
    const float* __restrict__ ux, const float* __restrict__ emb1,
    const float* __restrict__ nmT, const int* __restrict__ ei,
    const int* __restrict__ off, const int* __restrict__ elist,
    const float* __restrict__ epsp, float* __restrict__ outB, int N) {
    int n = blockIdx.x, j = threadIdx.x;
    float acc[8] = {0, 0, 0, 0, 0, 0, 0, 0};
    int e0 = off[n], e1 = off[n + 1];
    for (int idx = e0; idx < e1; ++idx) {
        int e = elist[idx];
        int s = ei[e];
        float em = emb1[(size_t)e * H + j];
        float4 m0 = *(const float4*)(nmT + s * 8);
        float4 m1 = *(const float4*)(nmT + s * 8 + 4);
        float mm[8] = {m0.x, m0.y, m0.z, m0.w, m1.x, m1.y, m1.z, m1.w};
#pragma unroll
        for (int rc = 0; rc < 8; ++rc) {
            float g = gelu_exact(ux[((size_t)rc * N + s) * H + j] + em);
            acc[rc] += g * mm[rc];
        }
    }
    float ev = 1.0f + epsp[1];
    float4 mn0 = *(const float4*)(nmT + n * 8);
    float4 mn1 = *(const float4*)(nmT + n * 8 + 4);
    float mn[8] = {mn0.x, mn0.y, mn0.z, mn0.w, mn1.x, mn1.y, mn1.z, mn1.w};
#pragma unroll
    for (int rc = 0; rc < 8; ++rc) {
        float h = ev * ux[((size_t)rc * N + n) * H + j] + mn[rc] * acc[rc];
        outB[((size_t)rc * N + n) * H + j] = h;
    }
}

// ---------------- fused MLP chain via bf16x3-split MFMA ----------------
// NG chained GEMMs (each: C = gelu(A @ W + b)), 64-row tile, full 128 cols.
// A split to bf16 hi/lo in LDS; W pre-split+transposed ([n][k] bf16) in global.
// Wave w owns cols [w*32, w*32+32), all 64 rows (4 row-tiles x 2 col-tiles).
template <int NG>
__global__ __launch_bounds__(256) void k_mlpf(
    const float* __restrict__ A, const unsigned short* __restrict__ Wsp,
    const float* __restrict__ bias0, const float* __restrict__ bias1,
    const float* __restrict__ bias2, float* __restrict__ C, int M) {
    __shared__ unsigned short Ah[64][136];   // +8 pad: rows advance 4 banks
    __shared__ unsigned short Al[64][136];
    const int tid = threadIdx.x;
    const int wave = tid >> 6, lane = tid & 63;
    const int crow = lane & 15, kgrp = lane >> 4;
    const int row0 = blockIdx.x * 64;
    // stage + split A
#pragma unroll
    for (int p = 0; p < 8; ++p) {
        int flat = p * 1024 + tid * 4;
        int r = flat >> 7, c = flat & 127;
        int rg = row0 + r; if (rg >= M) rg = M - 1;
        float4 v = *(const float4*)(A + (size_t)rg * H + c);
        ushort4 hh, ll;
        hh.x = f2bf(v.x); ll.x = f2bf(v.x - bf2f(hh.x));
        hh.y = f2bf(v.y); ll.y = f2bf(v.y - bf2f(hh.y));
        hh.z = f2bf(v.z); ll.z = f2bf(v.z - bf2f(hh.z));
        hh.w = f2bf(v.w); ll.w = f2bf(v.w - bf2f(hh.w));
        *(ushort4*)&Ah[r][c] = hh;
        *(ushort4*)&Al[r][c] = ll;
    }
    __syncthreads();
    const float* biases[3] = {bias0, bias1, bias2};
#pragma unroll
    for (int g = 0; g < NG; ++g) {
        const unsigned short* WhT = Wsp + (size_t)g * 32768;
        const unsigned short* WlT = WhT + 16384;
        f32x4 acc[4][2];
#pragma unroll
        for (int rt = 0; rt < 4; ++rt)
#pragma unroll
            for (int ct = 0; ct < 2; ++ct) acc[rt][ct] = (f32x4){0.f, 0.f, 0.f, 0.f};
        const int colb = wave * 32;
#pragma unroll
        for (int ks = 0; ks < 4; ++ks) {
            const int k0 = ks * 32 + kgrp * 8;
            short8v ah[4], al[4];
#pragma unroll
            for (int rt = 0; rt < 4; ++rt) {
                ah[rt] = *(const short8v*)&Ah[rt * 16 + crow][k0];
                al[rt] = *(const short8v*)&Al[rt * 16 + crow][k0];
            }
#pragma unroll
            for (int ct = 0; ct < 2; ++ct) {
                const int col = colb + ct * 16 + crow;
                short8v bh = *(const short8v*)(WhT + col * H + k0);
                short8v bl = *(const short8v*)(WlT + col * H + k0);
#pragma unroll
                for (int rt = 0; rt < 4; ++rt) {
                    acc[rt][ct] = mfma16(ah[rt], bh, acc[rt][ct]);
                    acc[rt][ct] = mfma16(ah[rt], bl, acc[rt][ct]);
                    acc[rt][ct] = mfma16(al[rt], bh, acc[rt][ct]);
                }
            }
        }
        const float* bias = biases[g];
        if (g < NG - 1) {
            __syncthreads();   // all waves done reading LDS for this gemm
#pragma unroll
            for (int rt = 0; rt < 4; ++rt)
#pragma unroll
                for (int ct = 0; ct < 2; ++ct) {
                    const int col = colb + ct * 16 + crow;
                    float bcol = bias[col];
#pragma unroll
                    for (int rr = 0; rr < 4; ++rr) {
                        int row = rt * 16 + kgrp * 4 + rr;
                        float v = gelu_exact(acc[rt][ct][rr] + bcol);
                        unsigned short h = f2bf(v);
                        Ah[row][col] = h;
                        Al[row][col] = f2bf(v - bf2f(h));
                    }
                }
            __syncthreads();
        } else {
#pragma unroll
            for (int rt = 0; rt < 4; ++rt)
#pragma unroll
                for (int ct = 0; ct < 2; ++ct) {
                    const int col = colb + ct * 16 + crow;
                    float bcol = bias[col];
#pragma unroll
                    for (int rr = 0; rr < 4; ++rr) {
                        int row = row0 + rt * 16 + kgrp * 4 + rr;
                        if (row < M)
                            C[(size_t)row * H + col] = gelu_exact(acc[rt][ct][rr] + bcol);
                    }
                }
        }
    }
}

// ---------------- pooling (in H-space; head2 is linear so it commutes) ----------------
__global__ __launch_bounds__(512) void k_pool_h(
    const float* __restrict__ hin, const float* __restrict__ nmT,
    const int* __restrict__ gstart, float* __restrict__ pooled,
    float* __restrict__ denb, int N, int G) {
    int g = blockIdx.x, r = blockIdx.y;
    int j = threadIdx.x & 127, q = threadIdx.x >> 7;   // 4 node stripes
    int n0 = gstart[g], n1 = gstart[g + 1];
    const float* hr = hin + (size_t)r * N * H;
    float num = 0.f, den = 0.f;
    for (int n = n0 + q; n < n1; n += 4) {
        float m = nmT[n * 8 + r];
        num += hr[(size_t)n * H + j] * m;
        den += m;
    }
    __shared__ float sn[512];
    __shared__ float sd[4];
    sn[threadIdx.x] = num;
    if (j == 0) sd[q] = den;
    __syncthreads();
    if (q == 0) {
        float numt = sn[j] + sn[128 + j] + sn[256 + j] + sn[384 + j];
        float dent = sd[0] + sd[1] + sd[2] + sd[3];
        pooled[((size_t)r * G + g) * H + j] = numt;
        if (j == 0) denb[r * G + g] = dent;
    }
}

// out[row][o] = (pooled[row] @ W2 + den*b2) / (den + 1e-7), row = rc*G+g
__global__ __launch_bounds__(128) void k_head2s(
    const float* __restrict__ pooled, const float* __restrict__ denb,
    const float* __restrict__ W, const float* __restrict__ bias,
    float* __restrict__ outp) {
    int row = blockIdx.x;
    int o = threadIdx.x & 31, kq = threadIdx.x >> 5;
    const float* p = pooled + (size_t)row * H;
    float acc = 0.f;
#pragma unroll
    for (int kk = 0; kk < 32; ++kk) {
        int k = kq * 32 + kk;
        acc += p[k] * W[k * OO + o];
    }
    __shared__ float s[128];
    s[threadIdx.x] = acc; __syncthreads();
    if (kq == 0) {
        float den = denb[row];
        float num = s[o] + s[32 + o] + s[64 + o] + s[96 + o] + den * bias[o];
        outp[row * OO + o] = num / (den + 1e-7f);
    }
}

extern "C" void kernel_launch(void* const* d_in, const int* in_sizes, int n_in,
                              void* d_out, int out_size, void* d_ws, size_t ws_size,
                              hipStream_t stream) {
    const float* x_feat = (const float*)d_in[0];
    const int*   ei     = (const int*)d_in[1];
    const float* eattr  = (const float*)d_in[2];
    const int*   batch  = (const int*)d_in[3];
    const float* nm     = (const float*)d_in[4];
    const float* atomW  = (const float*)d_in[5];
    const float* atomb  = (const float*)d_in[6];
    const float* epsp   = (const float*)d_in[7];
    const float* bondW  = (const float*)d_in[8];
    const float* bondb  = (const float*)d_in[9];
    const float* mlp1W  = (const float*)d_in[10];
    const float* mlp1b  = (const float*)d_in[11];
    const float* mlp2W  = (const float*)d_in[12];
    const float* mlp2b  = (const float*)d_in[13];
    const float* h1W    = (const float*)d_in[14];
    const float* h1b    = (const float*)d_in[15];
    const float* h2W    = (const float*)d_in[16];
    const float* h2b    = (const float*)d_in[17];

    const int N  = in_sizes[3];
    const int E  = in_sizes[1] / 2;
    const int G  = out_size / (RCN * OO);
    const int M  = RCN * N;

    float* x      = (float*)d_ws;
    float* emb    = x + (size_t)N * H;
    float* bufA   = emb + (size_t)2 * E * H;
    float* bufB   = bufA + (size_t)RCN * N * H;
    float* nmT    = bufB + (size_t)RCN * N * H;
    float* pooled = nmT + (size_t)N * RCN;
    float* denb   = pooled + (size_t)RCN * G * H;
    uintptr_t wa  = ((uintptr_t)(denb + RCN * G) + 15) & ~(uintptr_t)15;
    unsigned short* wsp = (unsigned short*)wa;        // 5 x (hi 16384 + lo 16384)
    int*   deg    = (int*)(wsp + 5 * 32768);
    int*   off    = deg + N;
    int*   cursor = off + N + 1;
    int*   elist  = cursor + N;
    int*   gstart = elist + E;

    // CSR by dst + graph ranges + transposed node mask
    k_zero_i32<<<(N + 255) / 256, 256, 0, stream>>>(deg, N);
    k_hist<<<(E + 255) / 256, 256, 0, stream>>>(ei, deg, E);
    k_scan<<<1, 1024, 0, stream>>>(deg, off, cursor, N);
    k_scatter<<<(E + 255) / 256, 256, 0, stream>>>(ei, cursor, elist, E);
    k_gstart<<<1, 128, 0, stream>>>(batch, gstart, N, G);
    k_nmt<<<(N * RCN + 255) / 256, 256, 0, stream>>>(nm, nmT, N);

    // weight split (order: mlp1_l0, mlp2_l0, mlp1_l1, mlp2_l1, head1)
    k_splitW<<<H, H, 0, stream>>>(mlp1W,         wsp + 0 * 32768, wsp + 0 * 32768 + 16384);
    k_splitW<<<H, H, 0, stream>>>(mlp2W,         wsp + 1 * 32768, wsp + 1 * 32768 + 16384);
    k_splitW<<<H, H, 0, stream>>>(mlp1W + H * H, wsp + 2 * 32768, wsp + 2 * 32768 + 16384);
    k_splitW<<<H, H, 0, stream>>>(mlp2W + H * H, wsp + 3 * 32768, wsp + 3 * 32768 + 16384);
    k_splitW<<<H, H, 0, stream>>>(h1W,           wsp + 4 * 32768, wsp + 4 * 32768 + 16384);

    // encoders
    k_atom<<<N, H, 0, stream>>>(x_feat, atomW, atomb, x, N);
    k_emb<<<dim3(E, 2), H, 0, stream>>>(eattr, bondW, bondb, emb, E);

    // layer 0: gather -> fused (mlp1 -> gelu -> mlp2 -> gelu)
    k_gather0<<<N, H, 0, stream>>>(x, emb, nmT, ei, off, elist, epsp, bufB, N);
    k_mlpf<2><<<(M + 63) / 64, 256, 0, stream>>>(bufB, wsp, mlp1b, mlp2b, nullptr, bufA, M);

    // layer 1: gather -> fused (mlp1 -> gelu -> mlp2 -> gelu -> head1 -> gelu)
    k_gather1<<<N, H, 0, stream>>>(bufA, emb + (size_t)E * H, nmT, ei, off, elist,
                                   epsp, bufB, N);
    k_mlpf<3><<<(M + 63) / 64, 256, 0, stream>>>(bufB, wsp + 2 * 32768,
                                                 mlp1b + H, mlp2b + H, h1b, bufA, M);

    // pool in H-space (head2 commuted past pooling), then tiny head2
    k_pool_h<<<dim3(G, RCN), 512, 0, stream>>>(bufA, nmT, gstart, pooled, denb, N, G);
    k_head2s<<<RCN * G, 128, 0, stream>>>(pooled, denb, h2W, h2b, (float*)d_out);
}

// Round 8
// 494.632 us; speedup vs baseline: 1.9294x; 1.1988x over previous
//
#include <hip/hip_runtime.h>
#include <hip/hip_bf16.h>

// GNN multi-edgeset: atom-enc -> 2x GINE(gather+agg, fused MLP) -> head -> masked mean pool
// fp32 I/O; GEMMs via bf16x3-split MFMA (16x16x32). H=128, Fe=16, Fin=64, L=2, O=32, RC=8.

#define H 128
#define FIN 64
#define FE 16
#define OO 32
#define RCN 8

typedef __attribute__((ext_vector_type(8))) short short8v;
typedef __attribute__((ext_vector_type(4))) float f32x4;

// exact-erf GELU via branch-free A&S 7.1.26 rational approx (|err_erf| < 1.5e-7)
__device__ __forceinline__ float gelu_fast(float v) {
    float z = v * 0.70710678118654752440f;
    float xa = fabsf(z);
    float t = __builtin_amdgcn_rcpf(fmaf(0.3275911f, xa, 1.0f));
    float p = t * (0.254829592f +
              t * (-0.284496736f +
              t * (1.421413741f +
              t * (-1.453152027f +
              t * 1.061405429f))));
    float e = __expf(-xa * xa);
    float er = fmaf(-p, e, 1.0f);       // erf(|z|)
    er = copysignf(er, z);
    return 0.5f * v * (1.0f + er);
}
__device__ __forceinline__ unsigned short f2bf(float f) {
    unsigned u = __float_as_uint(f);
    unsigned r = u + 0x7FFFu + ((u >> 16) & 1u);
    return (unsigned short)(r >> 16);
}
__device__ __forceinline__ float bf2f(unsigned short b) {
    return __uint_as_float(((unsigned)b) << 16);
}
__device__ __forceinline__ f32x4 mfma16(short8v a, short8v b, f32x4 c) {
    return __builtin_amdgcn_mfma_f32_16x16x32_bf16(a, b, c, 0, 0, 0);
}
// XOR-swizzled LDS index (shorts): row stride 128, 16B chunk index ^= row&7.
// Conflict-free for 16B-aligned b64/b128 access per 8-lane phase.
__device__ __forceinline__ int lds_idx(int r, int c) {
    return r * 128 + ((((c >> 3) ^ (r & 7)) << 3) | (c & 7));
}

// ---------------- CSR build ----------------
__global__ void k_zero_i32(int* p, int n) {
    int i = blockIdx.x * blockDim.x + threadIdx.x;
    if (i < n) p[i] = 0;
}

__global__ void k_hist(const int* __restrict__ ei, int* __restrict__ deg, int E) {
    int e = blockIdx.x * blockDim.x + threadIdx.x;
    if (e < E) atomicAdd(&deg[ei[E + e]], 1);   // dst
}

__global__ void k_scan(const int* __restrict__ deg, int* __restrict__ off,
                       int* __restrict__ cursor, int N) {
    __shared__ int s[1024];
    __shared__ int carry_s;
    int t = threadIdx.x;
    if (t == 0) { carry_s = 0; off[0] = 0; }
    __syncthreads();
    for (int base = 0; base < N; base += 1024) {
        int v = (base + t < N) ? deg[base + t] : 0;
        for (int d = 1; d < 1024; d <<= 1) {
            s[t] = v; __syncthreads();
            if (t >= d) v += s[t - d];
            __syncthreads();
        }
        int carry = carry_s;
        if (base + t < N) off[base + t + 1] = carry + v;
        __syncthreads();
        if (t == 1023) carry_s = carry + v;
        __syncthreads();
    }
    for (int i = t; i < N; i += 1024) cursor[i] = off[i];
}

__global__ void k_scatter(const int* __restrict__ ei, int* __restrict__ cursor,
                          int* __restrict__ elist, int E) {
    int e = blockIdx.x * blockDim.x + threadIdx.x;
    if (e < E) {
        int d = ei[E + e];
        int pos = atomicAdd(&cursor[d], 1);
        elist[pos] = e;
    }
}

__global__ void k_gstart(const int* __restrict__ batch, int* __restrict__ gstart,
                         int N, int G) {
    int g = blockIdx.x * blockDim.x + threadIdx.x;
    if (g > G) return;
    int lo = 0, hi = N;
    while (lo < hi) { int mid = (lo + hi) >> 1; if (batch[mid] < g) lo = mid + 1; else hi = mid; }
    gstart[g] = lo;
}

// node_mask [RC][N] -> nmT [N][RC]
__global__ void k_nmt(const float* __restrict__ nm, float* __restrict__ nmT, int N) {
    int idx = blockIdx.x * blockDim.x + threadIdx.x;
    if (idx < N * RCN) {
        int n = idx >> 3, rc = idx & 7;
        nmT[idx] = nm[rc * N + n];
    }
}

// ---------------- weight split: W[k][n] fp32 -> WhT/WlT [n][k] bf16 ----------------
__global__ __launch_bounds__(H) void k_splitW(const float* __restrict__ W,
                                              unsigned short* __restrict__ WhT,
                                              unsigned short* __restrict__ WlT) {
    int k = blockIdx.x, n = threadIdx.x;
    float v = W[k * H + n];
    unsigned short h = f2bf(v);
    WhT[n * H + k] = h;
    WlT[n * H + k] = f2bf(v - bf2f(h));
}

// ---------------- encoders ----------------
__global__ __launch_bounds__(H) void k_atom(const float* __restrict__ xf,
                                            const float* __restrict__ W,
                                            const float* __restrict__ b,
                                            float* __restrict__ x, int N) {
    int n = blockIdx.x, j = threadIdx.x;
    __shared__ float s[FIN];
    if (j < FIN) s[j] = xf[n * FIN + j];
    __syncthreads();
    float acc = b[j];
#pragma unroll
    for (int k = 0; k < FIN; k++) acc += s[k] * W[k * H + j];
    x[(size_t)n * H + j] = acc;
}

__global__ __launch_bounds__(H) void k_emb(const float* __restrict__ ea,
                                           const float* __restrict__ W,
                                           const float* __restrict__ b,
                                           float* __restrict__ emb, int E) {
    int e = blockIdx.x, l = blockIdx.y, j = threadIdx.x;
    __shared__ float s[FE];
    if (j < FE) s[j] = ea[e * FE + j];
    __syncthreads();
    float acc = b[l * H + j];
#pragma unroll
    for (int k = 0; k < FE; k++) acc += s[k] * W[(l * FE + k) * H + j];
    emb[((size_t)l * E + e) * H + j] = acc;
}

// ---------------- gather + aggregate ----------------
// layer 0: ux identical across rc -> compute gelu once per edge
__global__ __launch_bounds__(H) void k_gather0(
    const float* __restrict__ x, const float* __restrict__ emb0,
    const float* __restrict__ nmT, const int* __restrict__ ei,
    const int* __restrict__ off, const int* __restrict__ elist,
    const float* __restrict__ epsp, float* __restrict__ outB, int N) {
    int n = blockIdx.x, j = threadIdx.x;
    float xj = x[(size_t)n * H + j];
    float acc[8] = {0, 0, 0, 0, 0, 0, 0, 0};
    int e0 = off[n], e1 = off[n + 1];
    for (int idx = e0; idx < e1; ++idx) {
        int e = elist[idx];
        int s = ei[e];   // src
        float g = gelu_fast(x[(size_t)s * H + j] + emb0[(size_t)e * H + j]);
        float4 m0 = *(const float4*)(nmT + s * 8);
        float4 m1 = *(const float4*)(nmT + s * 8 + 4);
        acc[0] += g * m0.x; acc[1] += g * m0.y; acc[2] += g * m0.z; acc[3] += g * m0.w;
        acc[4] += g * m1.x; acc[5] += g * m1.y; acc[6] += g * m1.z; acc[7] += g * m1.w;
    }
    float ev = 1.0f + epsp[0];
    float4 mn0 = *(const float4*)(nmT + n * 8);
    float4 mn1 = *(const float4*)(nmT + n * 8 + 4);
    float mn[8] = {mn0.x, mn0.y, mn0.z, mn0.w, mn1.x, mn1.y, mn1.z, mn1.w};
#pragma unroll
    for (int rc = 0; rc < 8; ++rc)
        outB[((size_t)rc * N + n) * H + j] = ev * xj + mn[rc] * acc[rc];
}

// layer 1: all 8 rc in one block -> emb read ONCE per edge
__global__ __launch_bounds__(H) void k_gather1(
    const float* __restrict__ ux, const float* __restrict__ emb1,
    const float* __restrict__ nmT, const int* __restrict__ ei,
    const int* __restrict__ off, const int* __restrict__ elist,
    const float* __restrict__ epsp, float* __restrict__ outB, int N) {
    int n = blockIdx.x, j = threadIdx.x;
    float acc[8] = {0, 0, 0, 0, 0, 0, 0, 0};
    int e0 = off[n], e1 = off[n + 1];
    for (int idx = e0; idx < e1; ++idx) {
        int e = elist[idx];
        int s = ei[e];
        float em = emb1[(size_t)e * H + j];
        float4 m0 = *(const float4*)(nmT + s * 8);
        float4 m1 = *(const float4*)(nmT + s * 8 + 4);
        float mm[8] = {m0.x, m0.y, m0.z, m0.w, m1.x, m1.y, m1.z, m1.w};
#pragma unroll
        for (int rc = 0; rc < 8; ++rc) {
            float g = gelu_fast(ux[((size_t)rc * N + s) * H + j] + em);
            acc[rc] += g * mm[rc];
        }
    }
    float ev = 1.0f + epsp[1];
    float4 mn0 = *(const float4*)(nmT + n * 8);
    float4 mn1 = *(const float4*)(nmT + n * 8 + 4);
    float mn[8] = {mn0.x, mn0.y, mn0.z, mn0.w, mn1.x, mn1.y, mn1.z, mn1.w};
#pragma unroll
    for (int rc = 0; rc < 8; ++rc) {
        float h = ev * ux[((size_t)rc * N + n) * H + j] + mn[rc] * acc[rc];
        outB[((size_t)rc * N + n) * H + j] = h;
    }
}

// ---------------- fused MLP chain via bf16x3-split MFMA ----------------
// NG chained GEMMs (each: C = gelu(A @ W + b)), 64-row tile, full 128 cols.
// A split to bf16 hi/lo in XOR-swizzled LDS; W pre-split+transposed ([n][k] bf16).
// Wave w owns cols [w*32, w*32+32), all 64 rows (4 row-tiles x 2 col-tiles).
template <int NG>
__global__ __launch_bounds__(256) void k_mlpf(
    const float* __restrict__ A, const unsigned short* __restrict__ Wsp,
    const float* __restrict__ bias0, const float* __restrict__ bias1,
    const float* __restrict__ bias2, float* __restrict__ C, int M) {
    __shared__ unsigned short Ah[64 * 128];   // XOR-swizzled, no pad
    __shared__ unsigned short Al[64 * 128];
    const int tid = threadIdx.x;
    const int wave = tid >> 6, lane = tid & 63;
    const int crow = lane & 15, kgrp = lane >> 4;
    const int row0 = blockIdx.x * 64;
    // stage + split A
#pragma unroll
    for (int p = 0; p < 8; ++p) {
        int flat = p * 1024 + tid * 4;
        int r = flat >> 7, c = flat & 127;
        int rg = row0 + r; if (rg >= M) rg = M - 1;
        float4 v = *(const float4*)(A + (size_t)rg * H + c);
        ushort4 hh, ll;
        hh.x = f2bf(v.x); ll.x = f2bf(v.x - bf2f(hh.x));
        hh.y = f2bf(v.y); ll.y = f2bf(v.y - bf2f(hh.y));
        hh.z = f2bf(v.z); ll.z = f2bf(v.z - bf2f(hh.z));
        hh.w = f2bf(v.w); ll.w = f2bf(v.w - bf2f(hh.w));
        int si = lds_idx(r, c);
        *(ushort4*)&Ah[si] = hh;
        *(ushort4*)&Al[si] = ll;
    }
    __syncthreads();
    const float* biases[3] = {bias0, bias1, bias2};
#pragma unroll
    for (int g = 0; g < NG; ++g) {
        const unsigned short* WhT = Wsp + (size_t)g * 32768;
        const unsigned short* WlT = WhT + 16384;
        f32x4 acc[4][2];
#pragma unroll
        for (int rt = 0; rt < 4; ++rt)
#pragma unroll
            for (int ct = 0; ct < 2; ++ct) acc[rt][ct] = (f32x4){0.f, 0.f, 0.f, 0.f};
        const int colb = wave * 32;
#pragma unroll
        for (int ks = 0; ks < 4; ++ks) {
            const int k0 = ks * 32 + kgrp * 8;
            short8v ah[4], al[4];
#pragma unroll
            for (int rt = 0; rt < 4; ++rt) {
                int si = lds_idx(rt * 16 + crow, k0);
                ah[rt] = *(const short8v*)&Ah[si];
                al[rt] = *(const short8v*)&Al[si];
            }
#pragma unroll
            for (int ct = 0; ct < 2; ++ct) {
                const int col = colb + ct * 16 + crow;
                short8v bh = *(const short8v*)(WhT + col * H + k0);
                short8v bl = *(const short8v*)(WlT + col * H + k0);
#pragma unroll
                for (int rt = 0; rt < 4; ++rt) {
                    acc[rt][ct] = mfma16(ah[rt], bh, acc[rt][ct]);
                    acc[rt][ct] = mfma16(ah[rt], bl, acc[rt][ct]);
                    acc[rt][ct] = mfma16(al[rt], bh, acc[rt][ct]);
                }
            }
        }
        const float* bias = biases[g];
        if (g < NG - 1) {
            __syncthreads();   // all waves done reading LDS for this gemm
#pragma unroll
            for (int rt = 0; rt < 4; ++rt)
#pragma unroll
                for (int ct = 0; ct < 2; ++ct) {
                    const int col = colb + ct * 16 + crow;
                    float bcol = bias[col];
#pragma unroll
                    for (int rr = 0; rr < 4; ++rr) {
                        int row = rt * 16 + kgrp * 4 + rr;
                        float v = gelu_fast(acc[rt][ct][rr] + bcol);
                        unsigned short h = f2bf(v);
                        int si = lds_idx(row, col);
                        Ah[si] = h;
                        Al[si] = f2bf(v - bf2f(h));
                    }
                }
            __syncthreads();
        } else {
#pragma unroll
            for (int rt = 0; rt < 4; ++rt)
#pragma unroll
                for (int ct = 0; ct < 2; ++ct) {
                    const int col = colb + ct * 16 + crow;
                    float bcol = bias[col];
#pragma unroll
                    for (int rr = 0; rr < 4; ++rr) {
                        int row = row0 + rt * 16 + kgrp * 4 + rr;
                        if (row < M)
                            C[(size_t)row * H + col] = gelu_fast(acc[rt][ct][rr] + bcol);
                    }
                }
        }
    }
}

// ---------------- pooling (in H-space; head2 is linear so it commutes) ----------------
__global__ __launch_bounds__(512) void k_pool_h(
    const float* __restrict__ hin, const float* __restrict__ nmT,
    const int* __restrict__ gstart, float* __restrict__ pooled,
    float* __restrict__ denb, int N, int G) {
    int g = blockIdx.x, r = blockIdx.y;
    int j = threadIdx.x & 127, q = threadIdx.x >> 7;   // 4 node stripes
    int n0 = gstart[g], n1 = gstart[g + 1];
    const float* hr = hin + (size_t)r * N * H;
    float num = 0.f, den = 0.f;
    for (int n = n0 + q; n < n1; n += 4) {
        float m = nmT[n * 8 + r];
        num += hr[(size_t)n * H + j] * m;
        den += m;
    }
    __shared__ float sn[512];
    __shared__ float sd[4];
    sn[threadIdx.x] = num;
    if (j == 0) sd[q] = den;
    __syncthreads();
    if (q == 0) {
        float numt = sn[j] + sn[128 + j] + sn[256 + j] + sn[384 + j];
        float dent = sd[0] + sd[1] + sd[2] + sd[3];
        pooled[((size_t)r * G + g) * H + j] = numt;
        if (j == 0) denb[r * G + g] = dent;
    }
}

// out[row][o] = (pooled[row] @ W2 + den*b2) / (den + 1e-7), row = rc*G+g
__global__ __launch_bounds__(128) void k_head2s(
    const float* __restrict__ pooled, const float* __restrict__ denb,
    const float* __restrict__ W, const float* __restrict__ bias,
    float* __restrict__ outp) {
    int row = blockIdx.x;
    int o = threadIdx.x & 31, kq = threadIdx.x >> 5;
    const float* p = pooled + (size_t)row * H;
    float acc = 0.f;
#pragma unroll
    for (int kk = 0; kk < 32; ++kk) {
        int k = kq * 32 + kk;
        acc += p[k] * W[k * OO + o];
    }
    __shared__ float s[128];
    s[threadIdx.x] = acc; __syncthreads();
    if (kq == 0) {
        float den = denb[row];
        float num = s[o] + s[32 + o] + s[64 + o] + s[96 + o] + den * bias[o];
        outp[row * OO + o] = num / (den + 1e-7f);
    }
}

extern "C" void kernel_launch(void* const* d_in, const int* in_sizes, int n_in,
                              void* d_out, int out_size, void* d_ws, size_t ws_size,
                              hipStream_t stream) {
    const float* x_feat = (const float*)d_in[0];
    const int*   ei     = (const int*)d_in[1];
    const float* eattr  = (const float*)d_in[2];
    const int*   batch  = (const int*)d_in[3];
    const float* nm     = (const float*)d_in[4];
    const float* atomW  = (const float*)d_in[5];
    const float* atomb  = (const float*)d_in[6];
    const float* epsp   = (const float*)d_in[7];
    const float* bondW  = (const float*)d_in[8];
    const float* bondb  = (const float*)d_in[9];
    const float* mlp1W  = (const float*)d_in[10];
    const float* mlp1b  = (const float*)d_in[11];
    const float* mlp2W  = (const float*)d_in[12];
    const float* mlp2b  = (const float*)d_in[13];
    const float* h1W    = (const float*)d_in[14];
    const float* h1b    = (const float*)d_in[15];
    const float* h2W    = (const float*)d_in[16];
    const float* h2b    = (const float*)d_in[17];

    const int N  = in_sizes[3];
    const int E  = in_sizes[1] / 2;
    const int G  = out_size / (RCN * OO);
    const int M  = RCN * N;

    float* x      = (float*)d_ws;
    float* emb    = x + (size_t)N * H;
    float* bufA   = emb + (size_t)2 * E * H;
    float* bufB   = bufA + (size_t)RCN * N * H;
    float* nmT    = bufB + (size_t)RCN * N * H;
    float* pooled = nmT + (size_t)N * RCN;
    float* denb   = pooled + (size_t)RCN * G * H;
    uintptr_t wa  = ((uintptr_t)(denb + RCN * G) + 15) & ~(uintptr_t)15;
    unsigned short* wsp = (unsigned short*)wa;        // 5 x (hi 16384 + lo 16384)
    int*   deg    = (int*)(wsp + 5 * 32768);
    int*   off    = deg + N;
    int*   cursor = off + N + 1;
    int*   elist  = cursor + N;
    int*   gstart = elist + E;

    // CSR by dst + graph ranges + transposed node mask
    k_zero_i32<<<(N + 255) / 256, 256, 0, stream>>>(deg, N);
    k_hist<<<(E + 255) / 256, 256, 0, stream>>>(ei, deg, E);
    k_scan<<<1, 1024, 0, stream>>>(deg, off, cursor, N);
    k_scatter<<<(E + 255) / 256, 256, 0, stream>>>(ei, cursor, elist, E);
    k_gstart<<<1, 128, 0, stream>>>(batch, gstart, N, G);
    k_nmt<<<(N * RCN + 255) / 256, 256, 0, stream>>>(nm, nmT, N);

    // weight split (order: mlp1_l0, mlp2_l0, mlp1_l1, mlp2_l1, head1)
    k_splitW<<<H, H, 0, stream>>>(mlp1W,         wsp + 0 * 32768, wsp + 0 * 32768 + 16384);
    k_splitW<<<H, H, 0, stream>>>(mlp2W,         wsp + 1 * 32768, wsp + 1 * 32768 + 16384);
    k_splitW<<<H, H, 0, stream>>>(mlp1W + H * H, wsp + 2 * 32768, wsp + 2 * 32768 + 16384);
    k_splitW<<<H, H, 0, stream>>>(mlp2W + H * H, wsp + 3 * 32768, wsp + 3 * 32768 + 16384);
    k_splitW<<<H, H, 0, stream>>>(h1W,           wsp + 4 * 32768, wsp + 4 * 32768 + 16384);

    // encoders
    k_atom<<<N, H, 0, stream>>>(x_feat, atomW, atomb, x, N);
    k_emb<<<dim3(E, 2), H, 0, stream>>>(eattr, bondW, bondb, emb, E);

    // layer 0: gather -> fused (mlp1 -> gelu -> mlp2 -> gelu)
    k_gather0<<<N, H, 0, stream>>>(x, emb, nmT, ei, off, elist, epsp, bufB, N);
    k_mlpf<2><<<(M + 63) / 64, 256, 0, stream>>>(bufB, wsp, mlp1b, mlp2b, nullptr, bufA, M);

    // layer 1: gather -> fused (mlp1 -> gelu -> mlp2 -> gelu -> head1 -> gelu)
    k_gather1<<<N, H, 0, stream>>>(bufA, emb + (size_t)E * H, nmT, ei, off, elist,
                                   epsp, bufB, N);
    k_mlpf<3><<<(M + 63) / 64, 256, 0, stream>>>(bufB, wsp + 2 * 32768,
                                                 mlp1b + H, mlp2b + H, h1b, bufA, M);

    // pool in H-space (head2 commuted past pooling), then tiny head2
    k_pool_h<<<dim3(G, RCN), 512, 0, stream>>>(bufA, nmT, gstart, pooled, denb, N, G);
    k_head2s<<<RCN * G, 128, 0, stream>>>(pooled, denb, h2W, h2b, (float*)d_out);
}

// Round 9
// 475.847 us; speedup vs baseline: 2.0056x; 1.0395x over previous
//
#include <hip/hip_runtime.h>
#include <hip/hip_bf16.h>

// GNN multi-edgeset: atom-enc -> 2x GINE(gather+agg, fused MLP) -> head -> masked mean pool
// fp32 I/O; GEMMs via bf16x3-split MFMA (16x16x32) with SWAPPED operands
// (D = W^T_frag x A_frag) so each lane owns 4 adjacent C-columns -> packed
// cvt_pk epilogue + dwordx4 stores. H=128, Fe=16, Fin=64, L=2, O=32, RC=8.

#define H 128
#define FIN 64
#define FE 16
#define OO 32
#define RCN 8

typedef __attribute__((ext_vector_type(8))) short short8v;
typedef __attribute__((ext_vector_type(4))) float f32x4;

// exact-erf GELU via branch-free A&S 7.1.26 rational approx (|err_erf| < 1.5e-7)
__device__ __forceinline__ float gelu_fast(float v) {
    float z = v * 0.70710678118654752440f;
    float xa = fabsf(z);
    float t = __builtin_amdgcn_rcpf(fmaf(0.3275911f, xa, 1.0f));
    float p = t * (0.254829592f +
              t * (-0.284496736f +
              t * (1.421413741f +
              t * (-1.453152027f +
              t * 1.061405429f))));
    float e = __expf(-xa * xa);
    float er = fmaf(-p, e, 1.0f);       // erf(|z|)
    er = copysignf(er, z);
    return 0.5f * v * (1.0f + er);
}
__device__ __forceinline__ unsigned short f2bf(float f) {
    unsigned u = __float_as_uint(f);
    unsigned r = u + 0x7FFFu + ((u >> 16) & 1u);
    return (unsigned short)(r >> 16);
}
__device__ __forceinline__ float bf2f(unsigned short b) {
    return __uint_as_float(((unsigned)b) << 16);
}
// packed f32x2 -> bf16x2 (D.lo = bf16(a), D.hi = bf16(b)); hi/lo split is
// self-correcting so the hw rounding mode of this cvt doesn't affect accuracy
__device__ __forceinline__ unsigned cvt_pk_bf16(float a, float b) {
    unsigned r;
    asm("v_cvt_pk_bf16_f32 %0, %1, %2" : "=v"(r) : "v"(a), "v"(b));
    return r;
}
__device__ __forceinline__ f32x4 mfma16(short8v a, short8v b, f32x4 c) {
    return __builtin_amdgcn_mfma_f32_16x16x32_bf16(a, b, c, 0, 0, 0);
}
// XOR-swizzled LDS index (shorts): row stride 128, 16B chunk index ^= row&7.
__device__ __forceinline__ int lds_idx(int r, int c) {
    return r * 128 + ((((c >> 3) ^ (r & 7)) << 3) | (c & 7));
}

// ---------------- CSR build ----------------
__global__ void k_zero_i32(int* p, int n) {
    int i = blockIdx.x * blockDim.x + threadIdx.x;
    if (i < n) p[i] = 0;
}

__global__ void k_hist(const int* __restrict__ ei, int* __restrict__ deg, int E) {
    int e = blockIdx.x * blockDim.x + threadIdx.x;
    if (e < E) atomicAdd(&deg[ei[E + e]], 1);   // dst
}

__global__ void k_scan(const int* __restrict__ deg, int* __restrict__ off,
                       int* __restrict__ cursor, int N) {
    __shared__ int s[1024];
    __shared__ int carry_s;
    int t = threadIdx.x;
    if (t == 0) { carry_s = 0; off[0] = 0; }
    __syncthreads();
    for (int base = 0; base < N; base += 1024) {
        int v = (base + t < N) ? deg[base + t] : 0;
        for (int d = 1; d < 1024; d <<= 1) {
            s[t] = v; __syncthreads();
            if (t >= d) v += s[t - d];
            __syncthreads();
        }
        int carry = carry_s;
        if (base + t < N) off[base + t + 1] = carry + v;
        __syncthreads();
        if (t == 1023) carry_s = carry + v;
        __syncthreads();
    }
    for (int i = t; i < N; i += 1024) cursor[i] = off[i];
}

__global__ void k_scatter(const int* __restrict__ ei, int* __restrict__ cursor,
                          int* __restrict__ elist, int E) {
    int e = blockIdx.x * blockDim.x + threadIdx.x;
    if (e < E) {
        int d = ei[E + e];
        int pos = atomicAdd(&cursor[d], 1);
        elist[pos] = e;
    }
}

__global__ void k_gstart(const int* __restrict__ batch, int* __restrict__ gstart,
                         int N, int G) {
    int g = blockIdx.x * blockDim.x + threadIdx.x;
    if (g > G) return;
    int lo = 0, hi = N;
    while (lo < hi) { int mid = (lo + hi) >> 1; if (batch[mid] < g) lo = mid + 1; else hi = mid; }
    gstart[g] = lo;
}

// node_mask [RC][N] -> nmT [N][RC]
__global__ void k_nmt(const float* __restrict__ nm, float* __restrict__ nmT, int N) {
    int idx = blockIdx.x * blockDim.x + threadIdx.x;
    if (idx < N * RCN) {
        int n = idx >> 3, rc = idx & 7;
        nmT[idx] = nm[rc * N + n];
    }
}

// ---------------- weight split: W[k][n] fp32 -> WhT/WlT [n][k] bf16 ----------------
__global__ __launch_bounds__(H) void k_splitW(const float* __restrict__ W,
                                              unsigned short* __restrict__ WhT,
                                              unsigned short* __restrict__ WlT) {
    int k = blockIdx.x, n = threadIdx.x;
    float v = W[k * H + n];
    unsigned short h = f2bf(v);
    WhT[n * H + k] = h;
    WlT[n * H + k] = f2bf(v - bf2f(h));
}

// ---------------- encoders ----------------
__global__ __launch_bounds__(H) void k_atom(const float* __restrict__ xf,
                                            const float* __restrict__ W,
                                            const float* __restrict__ b,
                                            float* __restrict__ x, int N) {
    int n = blockIdx.x, j = threadIdx.x;
    __shared__ float s[FIN];
    if (j < FIN) s[j] = xf[n * FIN + j];
    __syncthreads();
    float acc = b[j];
#pragma unroll
    for (int k = 0; k < FIN; k++) acc += s[k] * W[k * H + j];
    x[(size_t)n * H + j] = acc;
}

__global__ __launch_bounds__(H) void k_emb(const float* __restrict__ ea,
                                           const float* __restrict__ W,
                                           const float* __restrict__ b,
                                           float* __restrict__ emb, int E) {
    int e = blockIdx.x, l = blockIdx.y, j = threadIdx.x;
    __shared__ float s[FE];
    if (j < FE) s[j] = ea[e * FE + j];
    __syncthreads();
    float acc = b[l * H + j];
#pragma unroll
    for (int k = 0; k < FE; k++) acc += s[k] * W[(l * FE + k) * H + j];
    emb[((size_t)l * E + e) * H + j] = acc;
}

// ---------------- gather + aggregate ----------------
// layer 0: ux identical across rc -> compute gelu once per edge
__global__ __launch_bounds__(H) void k_gather0(
    const float* __restrict__ x, const float* __restrict__ emb0,
    const float* __restrict__ nmT, const int* __restrict__ ei,
    const int* __restrict__ off, const int* __restrict__ elist,
    const float* __restrict__ epsp, float* __restrict__ outB, int N) {
    int n = blockIdx.x, j = threadIdx.x;
    float xj = x[(size_t)n * H + j];
    float acc[8] = {0, 0, 0, 0, 0, 0, 0, 0};
    int e0 = off[n], e1 = off[n + 1];
    for (int idx = e0; idx < e1; ++idx) {
        int e = elist[idx];
        int s = ei[e];   // src
        float g = gelu_fast(x[(size_t)s * H + j] + emb0[(size_t)e * H + j]);
        float4 m0 = *(const float4*)(nmT + s * 8);
        float4 m1 = *(const float4*)(nmT + s * 8 + 4);
        acc[0] += g * m0.x; acc[1] += g * m0.y; acc[2] += g * m0.z; acc[3] += g * m0.w;
        acc[4] += g * m1.x; acc[5] += g * m1.y; acc[6] += g * m1.z; acc[7] += g * m1.w;
    }
    float ev = 1.0f + epsp[0];
    float4 mn0 = *(const float4*)(nmT + n * 8);
    float4 mn1 = *(const float4*)(nmT + n * 8 + 4);
    float mn[8] = {mn0.x, mn0.y, mn0.z, mn0.w, mn1.x, mn1.y, mn1.z, mn1.w};
#pragma unroll
    for (int rc = 0; rc < 8; ++rc)
        outB[((size_t)rc * N + n) * H + j] = ev * xj + mn[rc] * acc[rc];
}

// layer 1: all 8 rc in one block -> emb read ONCE per edge
__global__ __launch_bounds__(H) void k_gather1(
    const float* __restrict__ ux, const float* __restrict__ emb1,
    const float* __restrict__ nmT, const int* __restrict__ ei,
    const int* __restrict__ off, const int* __restrict__ elist,
    const float* __restrict__ epsp, float* __restrict__ outB, int N) {
    int n = blockIdx.x, j = threadIdx.x;
    float acc[8] = {0, 0, 0, 0, 0, 0, 0, 0};
    int e0 = off[n], e1 = off[n + 1];
    for (int idx = e0; idx < e1; ++idx) {
        int e = elist[idx];
        int s = ei[e];
        float em = emb1[(size_t)e * H + j];
        float4 m0 = *(const float4*)(nmT + s * 8);
        float4 m1 = *(const float4*)(nmT + s * 8 + 4);
        float mm[8] = {m0.x, m0.y, m0.z, m0.w, m1.x, m1.y, m1.z, m1.w};
#pragma unroll
        for (int rc = 0; rc < 8; ++rc) {
            float g = gelu_fast(ux[((size_t)rc * N + s) * H + j] + em);
            acc[rc] += g * mm[rc];
        }
    }
    float ev = 1.0f + epsp[1];
    float4 mn0 = *(const float4*)(nmT + n * 8);
    float4 mn1 = *(const float4*)(nmT + n * 8 + 4);
    float mn[8] = {mn0.x, mn0.y, mn0.z, mn0.w, mn1.x, mn1.y, mn1.z, mn1.w};
#pragma unroll
    for (int rc = 0; rc < 8; ++rc) {
        float h = ev * ux[((size_t)rc * N + n) * H + j] + mn[rc] * acc[rc];
        outB[((size_t)rc * N + n) * H + j] = h;
    }
}

// ---------------- fused MLP chain via bf16x3-split MFMA (swapped operands) -----
// NG chained GEMMs (each: C = gelu(A @ W + b)), 64-row tile, full 128 cols.
// mfma(W_frag, A_frag): lane holds C[row = rt*16 + crow][col = colb+ct*16+kgrp*4 + r]
// -> 4 adjacent cols per lane: packed cvt_pk split, b64 LDS writes, dwordx4 C-store.
template <int NG>
__global__ __launch_bounds__(256) void k_mlpf(
    const float* __restrict__ A, const unsigned short* __restrict__ Wsp,
    const float* __restrict__ bias0, const float* __restrict__ bias1,
    const float* __restrict__ bias2, float* __restrict__ C, int M) {
    __shared__ unsigned short Ah[64 * 128];   // XOR-swizzled, no pad
    __shared__ unsigned short Al[64 * 128];
    const int tid = threadIdx.x;
    const int wave = tid >> 6, lane = tid & 63;
    const int crow = lane & 15, kgrp = lane >> 4;
    const int row0 = blockIdx.x * 64;
    // stage + split A (packed)
#pragma unroll
    for (int p = 0; p < 8; ++p) {
        int flat = p * 1024 + tid * 4;
        int r = flat >> 7, c = flat & 127;           // 4 adjacent cols per thread
        int rg = row0 + r; if (rg >= M) rg = M - 1;
        float4 v = *(const float4*)(A + (size_t)rg * H + c);
        unsigned h01 = cvt_pk_bf16(v.x, v.y);
        unsigned h23 = cvt_pk_bf16(v.z, v.w);
        float f0 = __uint_as_float(h01 << 16), f1 = __uint_as_float(h01 & 0xffff0000u);
        float f2 = __uint_as_float(h23 << 16), f3 = __uint_as_float(h23 & 0xffff0000u);
        unsigned l01 = cvt_pk_bf16(v.x - f0, v.y - f1);
        unsigned l23 = cvt_pk_bf16(v.z - f2, v.w - f3);
        int si = lds_idx(r, c);                      // 8B-aligned (c&7 in {0,4}... c%4==0)
        *(uint2*)&Ah[si] = (uint2){h01, h23};
        *(uint2*)&Al[si] = (uint2){l01, l23};
    }
    __syncthreads();
    const float* biases[3] = {bias0, bias1, bias2};
#pragma unroll
    for (int g = 0; g < NG; ++g) {
        const unsigned short* WhT = Wsp + (size_t)g * 32768;
        const unsigned short* WlT = WhT + 16384;
        f32x4 acc[4][2];
#pragma unroll
        for (int rt = 0; rt < 4; ++rt)
#pragma unroll
            for (int ct = 0; ct < 2; ++ct) acc[rt][ct] = (f32x4){0.f, 0.f, 0.f, 0.f};
        const int colb = wave * 32;
#pragma unroll
        for (int ks = 0; ks < 4; ++ks) {
            const int k0 = ks * 32 + kgrp * 8;
            short8v ah[4], al[4];
#pragma unroll
            for (int rt = 0; rt < 4; ++rt) {
                int si = lds_idx(rt * 16 + crow, k0);
                ah[rt] = *(const short8v*)&Ah[si];
                al[rt] = *(const short8v*)&Al[si];
            }
#pragma unroll
            for (int ct = 0; ct < 2; ++ct) {
                const int col = colb + ct * 16 + crow;
                short8v bh = *(const short8v*)(WhT + col * H + k0);
                short8v bl = *(const short8v*)(WlT + col * H + k0);
#pragma unroll
                for (int rt = 0; rt < 4; ++rt) {
                    // swapped operands: D = W^T_frag x A_frag  (C^T fragment layout)
                    acc[rt][ct] = mfma16(bh, ah[rt], acc[rt][ct]);
                    acc[rt][ct] = mfma16(bl, ah[rt], acc[rt][ct]);
                    acc[rt][ct] = mfma16(bh, al[rt], acc[rt][ct]);
                }
            }
        }
        const float* bias = biases[g];
        // per-lane bias: 4 adjacent cols at colb + ct*16 + kgrp*4
        float4 bb[2];
#pragma unroll
        for (int ct = 0; ct < 2; ++ct)
            bb[ct] = *(const float4*)(bias + colb + ct * 16 + kgrp * 4);
        if (g < NG - 1) {
            __syncthreads();   // all waves done reading LDS for this gemm
#pragma unroll
            for (int rt = 0; rt < 4; ++rt)
#pragma unroll
                for (int ct = 0; ct < 2; ++ct) {
                    int row = rt * 16 + crow;
                    int col0 = colb + ct * 16 + kgrp * 4;
                    float v0 = gelu_fast(acc[rt][ct][0] + bb[ct].x);
                    float v1 = gelu_fast(acc[rt][ct][1] + bb[ct].y);
                    float v2 = gelu_fast(acc[rt][ct][2] + bb[ct].z);
                    float v3 = gelu_fast(acc[rt][ct][3] + bb[ct].w);
                    unsigned h01 = cvt_pk_bf16(v0, v1);
                    unsigned h23 = cvt_pk_bf16(v2, v3);
                    float f0 = __uint_as_float(h01 << 16), f1 = __uint_as_float(h01 & 0xffff0000u);
                    float f2 = __uint_as_float(h23 << 16), f3 = __uint_as_float(h23 & 0xffff0000u);
                    unsigned l01 = cvt_pk_bf16(v0 - f0, v1 - f1);
                    unsigned l23 = cvt_pk_bf16(v2 - f2, v3 - f3);
                    int si = lds_idx(row, col0);
                    *(uint2*)&Ah[si] = (uint2){h01, h23};
                    *(uint2*)&Al[si] = (uint2){l01, l23};
                }
            __syncthreads();
        } else {
#pragma unroll
            for (int rt = 0; rt < 4; ++rt)
#pragma unroll
                for (int ct = 0; ct < 2; ++ct) {
                    int row = row0 + rt * 16 + crow;
                    int col0 = colb + ct * 16 + kgrp * 4;
                    if (row < M) {
                        float4 o;
                        o.x = gelu_fast(acc[rt][ct][0] + bb[ct].x);
                        o.y = gelu_fast(acc[rt][ct][1] + bb[ct].y);
                        o.z = gelu_fast(acc[rt][ct][2] + bb[ct].z);
                        o.w = gelu_fast(acc[rt][ct][3] + bb[ct].w);
                        *(float4*)(C + (size_t)row * H + col0) = o;
                    }
                }
        }
    }
}

// ---------------- pooling (in H-space; head2 is linear so it commutes) ----------------
__global__ __launch_bounds__(512) void k_pool_h(
    const float* __restrict__ hin, const float* __restrict__ nmT,
    const int* __restrict__ gstart, float* __restrict__ pooled,
    float* __restrict__ denb, int N, int G) {
    int g = blockIdx.x, r = blockIdx.y;
    int j = threadIdx.x & 127, q = threadIdx.x >> 7;   // 4 node stripes
    int n0 = gstart[g], n1 = gstart[g + 1];
    const float* hr = hin + (size_t)r * N * H;
    float num = 0.f, den = 0.f;
    for (int n = n0 + q; n < n1; n += 4) {
        float m = nmT[n * 8 + r];
        num += hr[(size_t)n * H + j] * m;
        den += m;
    }
    __shared__ float sn[512];
    __shared__ float sd[4];
    sn[threadIdx.x] = num;
    if (j == 0) sd[q] = den;
    __syncthreads();
    if (q == 0) {
        float numt = sn[j] + sn[128 + j] + sn[256 + j] + sn[384 + j];
        float dent = sd[0] + sd[1] + sd[2] + sd[3];
        pooled[((size_t)r * G + g) * H + j] = numt;
        if (j == 0) denb[r * G + g] = dent;
    }
}

// out[row][o] = (pooled[row] @ W2 + den*b2) / (den + 1e-7), row = rc*G+g
__global__ __launch_bounds__(128) void k_head2s(
    const float* __restrict__ pooled, const float* __restrict__ denb,
    const float* __restrict__ W, const float* __restrict__ bias,
    float* __restrict__ outp) {
    int row = blockIdx.x;
    int o = threadIdx.x & 31, kq = threadIdx.x >> 5;
    const float* p = pooled + (size_t)row * H;
    float acc = 0.f;
#pragma unroll
    for (int kk = 0; kk < 32; ++kk) {
        int k = kq * 32 + kk;
        acc += p[k] * W[k * OO + o];
    }
    __shared__ float s[128];
    s[threadIdx.x] = acc; __syncthreads();
    if (kq == 0) {
        float den = denb[row];
        float num = s[o] + s[32 + o] + s[64 + o] + s[96 + o] + den * bias[o];
        outp[row * OO + o] = num / (den + 1e-7f);
    }
}

extern "C" void kernel_launch(void* const* d_in, const int* in_sizes, int n_in,
                              void* d_out, int out_size, void* d_ws, size_t ws_size,
                              hipStream_t stream) {
    const float* x_feat = (const float*)d_in[0];
    const int*   ei     = (const int*)d_in[1];
    const float* eattr  = (const float*)d_in[2];
    const int*   batch  = (const int*)d_in[3];
    const float* nm     = (const float*)d_in[4];
    const float* atomW  = (const float*)d_in[5];
    const float* atomb  = (const float*)d_in[6];
    const float* epsp   = (const float*)d_in[7];
    const float* bondW  = (const float*)d_in[8];
    const float* bondb  = (const float*)d_in[9];
    const float* mlp1W  = (const float*)d_in[10];
    const float* mlp1b  = (const float*)d_in[11];
    const float* mlp2W  = (const float*)d_in[12];
    const float* mlp2b  = (const float*)d_in[13];
    const float* h1W    = (const float*)d_in[14];
    const float* h1b    = (const float*)d_in[15];
    const float* h2W    = (const float*)d_in[16];
    const float* h2b    = (const float*)d_in[17];

    const int N  = in_sizes[3];
    const int E  = in_sizes[1] / 2;
    const int G  = out_size / (RCN * OO);
    const int M  = RCN * N;

    float* x      = (float*)d_ws;
    float* emb    = x + (size_t)N * H;
    float* bufA   = emb + (size_t)2 * E * H;
    float* bufB   = bufA + (size_t)RCN * N * H;
    float* nmT    = bufB + (size_t)RCN * N * H;
    float* pooled = nmT + (size_t)N * RCN;
    float* denb   = pooled + (size_t)RCN * G * H;
    uintptr_t wa  = ((uintptr_t)(denb + RCN * G) + 15) & ~(uintptr_t)15;
    unsigned short* wsp = (unsigned short*)wa;        // 5 x (hi 16384 + lo 16384)
    int*   deg    = (int*)(wsp + 5 * 32768);
    int*   off    = deg + N;
    int*   cursor = off + N + 1;
    int*   elist  = cursor + N;
    int*   gstart = elist + E;

    // CSR by dst + graph ranges + transposed node mask
    k_zero_i32<<<(N + 255) / 256, 256, 0, stream>>>(deg, N);
    k_hist<<<(E + 255) / 256, 256, 0, stream>>>(ei, deg, E);
    k_scan<<<1, 1024, 0, stream>>>(deg, off, cursor, N);
    k_scatter<<<(E + 255) / 256, 256, 0, stream>>>(ei, cursor, elist, E);
    k_gstart<<<1, 128, 0, stream>>>(batch, gstart, N, G);
    k_nmt<<<(N * RCN + 255) / 256, 256, 0, stream>>>(nm, nmT, N);

    // weight split (order: mlp1_l0, mlp2_l0, mlp1_l1, mlp2_l1, head1)
    k_splitW<<<H, H, 0, stream>>>(mlp1W,         wsp + 0 * 32768, wsp + 0 * 32768 + 16384);
    k_splitW<<<H, H, 0, stream>>>(mlp2W,         wsp + 1 * 32768, wsp + 1 * 32768 + 16384);
    k_splitW<<<H, H, 0, stream>>>(mlp1W + H * H, wsp + 2 * 32768, wsp + 2 * 32768 + 16384);
    k_splitW<<<H, H, 0, stream>>>(mlp2W + H * H, wsp + 3 * 32768, wsp + 3 * 32768 + 16384);
    k_splitW<<<H, H, 0, stream>>>(h1W,           wsp + 4 * 32768, wsp + 4 * 32768 + 16384);

    // encoders
    k_atom<<<N, H, 0, stream>>>(x_feat, atomW, atomb, x, N);
    k_emb<<<dim3(E, 2), H, 0, stream>>>(eattr, bondW, bondb, emb, E);

    // layer 0: gather -> fused (mlp1 -> gelu -> mlp2 -> gelu)
    k_gather0<<<N, H, 0, stream>>>(x, emb, nmT, ei, off, elist, epsp, bufB, N);
    k_mlpf<2><<<(M + 63) / 64, 256, 0, stream>>>(bufB, wsp, mlp1b, mlp2b, nullptr, bufA, M);

    // layer 1: gather -> fused (mlp1 -> gelu -> mlp2 -> gelu -> head1 -> gelu)
    k_gather1<<<N, H, 0, stream>>>(bufA, emb + (size_t)E * H, nmT, ei, off, elist,
                                   epsp, bufB, N);
    k_mlpf<3><<<(M + 63) / 64, 256, 0, stream>>>(bufB, wsp + 2 * 32768,
                                                 mlp1b + H, mlp2b + H, h1b, bufA, M);

    // pool in H-space (head2 commuted past pooling), then tiny head2
    k_pool_h<<<dim3(G, RCN), 512, 0, stream>>>(bufA, nmT, gstart, pooled, denb, N, G);
    k_head2s<<<RCN * G, 128, 0, stream>>>(pooled, denb, h2W, h2b, (float*)d_out);
}